// Round 10
// baseline (116.854 us; speedup 1.0000x reference)
//
#include <hip/hip_runtime.h>
#include <hip/hip_bf16.h>

#define B_ 8
#define Q_ 128
#define K_ 256
#define D_ 512
#define TWOLOG2E 2.8853900817779268f
#define SCALE 0.044194173824159216f   // 1/sqrt(512)
#define L2E 1.4426950408889634f
#define MASKVAL (-44194173.824159216f) // -1e9 * SCALE

typedef __attribute__((ext_vector_type(8))) short frag8;   // 8 bf16
typedef __attribute__((ext_vector_type(4))) float f32x4;

__device__ __forceinline__ float fexp2(float x) {
  float r;
  asm("v_exp_f32 %0, %1" : "=v"(r) : "v"(x));
  return r;
}
__device__ __forceinline__ float frcp(float x) {
  float r;
  asm("v_rcp_f32 %0, %1" : "=v"(r) : "v"(x));
  return r;
}
__device__ __forceinline__ unsigned f2bf_u(float x) {
  unsigned u = __float_as_uint(x);
  return (u + 0x7FFFu + ((u >> 16) & 1u)) >> 16;
}
__device__ __forceinline__ unsigned short f2bf(float x) {
  return (unsigned short)f2bf_u(x);
}
__device__ __forceinline__ unsigned packbf(float lo, float hi) {
  return f2bf_u(lo) | (f2bf_u(hi) << 16);
}

// ---------------- Kernel 1: fused convert + MFMA projection GEMM ----------------
// (unchanged from R6)
__global__ __launch_bounds__(256) void gemm_kernel(
    const float* __restrict__ query, const float* __restrict__ key,
    const float* __restrict__ W1, const float* __restrict__ b1,
    float* __restrict__ qp, float* __restrict__ kpbT) {
  __shared__ short As[32 * 64];
  __shared__ short Bs[64 * 72];
  const int t = threadIdx.x;
  const int m0 = blockIdx.y * 32;
  const int n0 = blockIdx.x * 64;
  const bool is_k = (m0 >= B_ * Q_);
  const float* X = is_k ? key : query;
  const int xrow0 = is_k ? (m0 - B_ * Q_) : m0;
  const float* Wb = W1 + (is_k ? (size_t)D_ * D_ : 0);

  const int am = t >> 3;
  const int ac = t & 7;
  const float* gA = X + (size_t)(xrow0 + am) * D_ + ac * 8;
  short* aw = As + am * 64 + ((ac ^ (am & 7)) * 8);

  const int prow = t >> 4;
  const int n4 = (t & 15) * 4;
  const float* gB = Wb + n0 + n4;

  const int l = t & 63;
  const int w = t >> 6;
  const int lr = l & 15;
  const int kg = l >> 4;
  const int key8 = lr & 7;
  int aoff[2][2], boff[2];
#pragma unroll
  for (int kk = 0; kk < 2; ++kk) {
    const int cposA = ((kg + kk * 4) ^ key8) * 8;
#pragma unroll
    for (int mt = 0; mt < 2; ++mt) aoff[mt][kk] = (mt * 16 + lr) * 64 + cposA;
    boff[kk] = (w * 16 + lr) * 72 + (kg + kk * 4) * 8;
  }

  f32x4 acc[2];
  acc[0] = (f32x4){0.f, 0.f, 0.f, 0.f};
  acc[1] = (f32x4){0.f, 0.f, 0.f, 0.f};

  for (int k0 = 0; k0 < D_; k0 += 64) {
    float4 a0 = *(const float4*)(gA + k0);
    float4 a1 = *(const float4*)(gA + k0 + 4);
    float4 w00 = *(const float4*)(gB + (size_t)(k0 + 2 * prow) * D_);
    float4 w01 = *(const float4*)(gB + (size_t)(k0 + 2 * prow + 1) * D_);
    float4 w10 = *(const float4*)(gB + (size_t)(k0 + 2 * prow + 32) * D_);
    float4 w11 = *(const float4*)(gB + (size_t)(k0 + 2 * prow + 33) * D_);
    __syncthreads();
    {
      union { frag8 f; unsigned short u[8]; } av;
      av.u[0] = f2bf(a0.x); av.u[1] = f2bf(a0.y); av.u[2] = f2bf(a0.z); av.u[3] = f2bf(a0.w);
      av.u[4] = f2bf(a1.x); av.u[5] = f2bf(a1.y); av.u[6] = f2bf(a1.z); av.u[7] = f2bf(a1.w);
      *(frag8*)aw = av.f;
    }
    {
      float lo0[4] = {w00.x, w00.y, w00.z, w00.w};
      float hi0[4] = {w01.x, w01.y, w01.z, w01.w};
      float lo1[4] = {w10.x, w10.y, w10.z, w10.w};
      float hi1[4] = {w11.x, w11.y, w11.z, w11.w};
#pragma unroll
      for (int j = 0; j < 4; ++j) {
        *(unsigned*)(Bs + (n4 + j) * 72 + 2 * prow) = packbf(lo0[j], hi0[j]);
        *(unsigned*)(Bs + (n4 + j) * 72 + 2 * (prow + 16)) = packbf(lo1[j], hi1[j]);
      }
    }
    __syncthreads();
#pragma unroll
    for (int kk = 0; kk < 2; ++kk) {
      frag8 bf = *(const frag8*)(Bs + boff[kk]);
#pragma unroll
      for (int mt = 0; mt < 2; ++mt) {
        frag8 af = *(const frag8*)(As + aoff[mt][kk]);
        acc[mt] = __builtin_amdgcn_mfma_f32_16x16x32_bf16(af, bf, acc[mt], 0, 0, 0);
      }
    }
  }

  const int col = n0 + w * 16 + lr;
  if (is_k) {
    const float bc = b1[col];
#pragma unroll
    for (int mt = 0; mt < 2; ++mt) {
      const int krow = m0 - B_ * Q_ + mt * 16 + kg * 4;
      const int bb = krow >> 8;
      const int kk0 = krow & 255;
      float4 v;
      v.x = fexp2((acc[mt][0] + bc) * TWOLOG2E);
      v.y = fexp2((acc[mt][1] + bc) * TWOLOG2E);
      v.z = fexp2((acc[mt][2] + bc) * TWOLOG2E);
      v.w = fexp2((acc[mt][3] + bc) * TWOLOG2E);
      *(float4*)&kpbT[((size_t)bb * D_ + col) * K_ + kk0] = v;
    }
  } else {
#pragma unroll
    for (int mt = 0; mt < 2; ++mt) {
#pragma unroll
      for (int i = 0; i < 4; ++i) {
        const int row = m0 + mt * 16 + kg * 4 + i;
        qp[(size_t)row * D_ + col] = fexp2(acc[mt][i] * TWOLOG2E);
      }
    }
  }
}

// ---------------- Kernel 2: tanh-score (raw masked scores to scratch) ----------------
// qp holds Eq = e^{2 qproj}; kpbT holds Ek = e^{2(kproj+b1)}.
// Grid (64, 8): qt = bx>>1 (4 q-rows), kh = bx&1 (128-k half). 1024 thr =
// 16 waves; wave w covers h-chunk w*32 and all 128 k (2 k/lane, float2).
// 512 blocks = 2 blocks/CU = 32 waves/CU (full occupancy).
__global__ __launch_bounds__(1024) void score_kernel(
    const float* __restrict__ qp, const float* __restrict__ kpbT,
    const int* __restrict__ mask, const float* __restrict__ w2,
    float* __restrict__ sc) {
  __shared__ float smem_p[16 * 512];  // [w][q(4)][128]  32 KB
  const int b = blockIdx.y;
  const int qt = blockIdx.x >> 1;
  const int kh = blockIdx.x & 1;
  const int q0 = qt * 4;
  const int t = threadIdx.x;
  const int lane = t & 63;
  const int w = __builtin_amdgcn_readfirstlane(t >> 6);  // 0..15
  const int h0 = w * 32;

  // ---- phase 1: partials over (128 k, 32 h)
  {
    const float* pk = kpbT + ((size_t)b * D_ + h0) * K_ + kh * 128 + 2 * lane;
    const float* q_0 = qp + (size_t)(b * Q_ + q0 + 0) * D_ + h0;
    const float* q_1 = qp + (size_t)(b * Q_ + q0 + 1) * D_ + h0;
    const float* q_2 = qp + (size_t)(b * Q_ + q0 + 2) * D_ + h0;
    const float* q_3 = qp + (size_t)(b * Q_ + q0 + 3) * D_ + h0;
    const float* w2h = w2 + h0;

    float2 a0 = {0.f, 0.f}, a1 = {0.f, 0.f}, a2 = {0.f, 0.f}, a3 = {0.f, 0.f};
    for (int h = 0; h < 32; h += 8) {
      float2 kv[8];
#pragma unroll
      for (int j = 0; j < 8; ++j) kv[j] = *(const float2*)&pk[(size_t)(h + j) * K_];
      float4 e0a = *(const float4*)(q_0 + h), e0b = *(const float4*)(q_0 + h + 4);
      float4 e1a = *(const float4*)(q_1 + h), e1b = *(const float4*)(q_1 + h + 4);
      float4 e2a = *(const float4*)(q_2 + h), e2b = *(const float4*)(q_2 + h + 4);
      float4 e3a = *(const float4*)(q_3 + h), e3b = *(const float4*)(q_3 + h + 4);
      float4 wa = *(const float4*)(w2h + h), wb = *(const float4*)(w2h + h + 4);
      float E0[8] = {e0a.x, e0a.y, e0a.z, e0a.w, e0b.x, e0b.y, e0b.z, e0b.w};
      float E1[8] = {e1a.x, e1a.y, e1a.z, e1a.w, e1b.x, e1b.y, e1b.z, e1b.w};
      float E2[8] = {e2a.x, e2a.y, e2a.z, e2a.w, e2b.x, e2b.y, e2b.z, e2b.w};
      float E3[8] = {e3a.x, e3a.y, e3a.z, e3a.w, e3b.x, e3b.y, e3b.z, e3b.w};
      float WV[8] = {wa.x, wa.y, wa.z, wa.w, wb.x, wb.y, wb.z, wb.w};
#pragma unroll
      for (int j = 0; j < 8; ++j) {
        a0.x = fmaf(WV[j], frcp(fmaf(E0[j], kv[j].x, 1.f)), a0.x);
        a0.y = fmaf(WV[j], frcp(fmaf(E0[j], kv[j].y, 1.f)), a0.y);
        a1.x = fmaf(WV[j], frcp(fmaf(E1[j], kv[j].x, 1.f)), a1.x);
        a1.y = fmaf(WV[j], frcp(fmaf(E1[j], kv[j].y, 1.f)), a1.y);
        a2.x = fmaf(WV[j], frcp(fmaf(E2[j], kv[j].x, 1.f)), a2.x);
        a2.y = fmaf(WV[j], frcp(fmaf(E2[j], kv[j].y, 1.f)), a2.y);
        a3.x = fmaf(WV[j], frcp(fmaf(E3[j], kv[j].x, 1.f)), a3.x);
        a3.y = fmaf(WV[j], frcp(fmaf(E3[j], kv[j].y, 1.f)), a3.y);
      }
    }
    *(float2*)&smem_p[w * 512 + 0 * 128 + 2 * lane] = a0;
    *(float2*)&smem_p[w * 512 + 1 * 128 + 2 * lane] = a1;
    *(float2*)&smem_p[w * 512 + 2 * 128 + 2 * lane] = a2;
    *(float2*)&smem_p[w * 512 + 3 * 128 + 2 * lane] = a3;
  }
  __syncthreads();

  // ---- phase 2: combine across 16 waves; write raw masked scores
  if (w < 4) {
    const int q = w;
    float sw = 0.f;
#pragma unroll
    for (int m = 0; m < 8; ++m) sw += w2[lane + 64 * m];
#pragma unroll
    for (int off = 32; off; off >>= 1) sw += __shfl_xor(sw, off);

    float* srow = sc + (size_t)(b * Q_ + q0 + q) * K_ + kh * 128;
#pragma unroll
    for (int half = 0; half < 2; ++half) {
      const int pos = half * 64 + lane;
      float p = 0.f;
#pragma unroll
      for (int ww = 0; ww < 16; ++ww) p += smem_p[ww * 512 + q * 128 + pos];
      const int mk = mask[b * K_ + kh * 128 + pos];
      srow[pos] = mk ? MASKVAL : fmaf(-2.f, p, sw) * SCALE;
    }
  }
}

// ---------------- Kernel 3: softmax + PV GEMM ----------------
// grid (32, 8): qt = bx>>3 (32 q-rows), ct = bx&7 (64 cols). 1024 thr = 16 waves.
// Phase A: wave w softmaxes rows w*2, w*2+1 (lane -> 4 k, float4);
//          ct==0 blocks also write out_w. Phase B: PV from LDS weights.
__global__ __launch_bounds__(1024) void pv_kernel(
    const float* __restrict__ sc, const float* __restrict__ value,
    float* __restrict__ out_w, float* __restrict__ out_vec) {
  __shared__ float pw[32 * 256];  // 32 KB
  const int b = blockIdx.y;
  const int qt = blockIdx.x >> 3;
  const int ct = blockIdx.x & 7;
  const int t = threadIdx.x;
  const int lane = t & 63;
  const int w = __builtin_amdgcn_readfirstlane(t >> 6);  // 0..15

  // ---- phase A: softmax, 2 rows per wave
#pragma unroll
  for (int rr = 0; rr < 2; ++rr) {
    const int row = w * 2 + rr;
    const int q = qt * 32 + row;
    const float* srow = sc + (size_t)(b * Q_ + q) * K_;
    float4 sv = *(const float4*)&srow[lane * 4];
    float mx = fmaxf(fmaxf(sv.x, sv.y), fmaxf(sv.z, sv.w));
#pragma unroll
    for (int off = 32; off; off >>= 1) mx = fmaxf(mx, __shfl_xor(mx, off));
    float4 e;
    e.x = fexp2((sv.x - mx) * L2E);
    e.y = fexp2((sv.y - mx) * L2E);
    e.z = fexp2((sv.z - mx) * L2E);
    e.w = fexp2((sv.w - mx) * L2E);
    float sum = e.x + e.y + e.z + e.w;
#pragma unroll
    for (int off = 32; off; off >>= 1) sum += __shfl_xor(sum, off);
    const float inv = frcp(sum);
    float4 p;
    p.x = e.x * inv; p.y = e.y * inv; p.z = e.z * inv; p.w = e.w * inv;
    *(float4*)&pw[row * 256 + lane * 4] = p;
    if (ct == 0) *(float4*)&out_w[(size_t)(b * Q_ + q) * K_ + lane * 4] = p;
  }
  __syncthreads();

  // ---- phase B: PV. wave w -> q rows qt*32 + 2w, 2w+1; col = ct*64 + lane
  const int col = ct * 64 + lane;
  const float* pw0 = &pw[(w * 2) * 256];
  const float* pw1 = pw0 + 256;
  const float* vb = value + (size_t)b * K_ * D_ + col;

  float o0 = 0.f, o1 = 0.f;
  for (int k = 0; k < K_; k += 4) {
    const float4 p0 = *(const float4*)&pw0[k];  // LDS broadcast (uniform)
    const float4 p1 = *(const float4*)&pw1[k];
    const float v0 = vb[(size_t)(k + 0) * D_];
    const float v1 = vb[(size_t)(k + 1) * D_];
    const float v2 = vb[(size_t)(k + 2) * D_];
    const float v3 = vb[(size_t)(k + 3) * D_];
    o0 = fmaf(p0.x, v0, fmaf(p0.y, v1, fmaf(p0.z, v2, fmaf(p0.w, v3, o0))));
    o1 = fmaf(p1.x, v0, fmaf(p1.y, v1, fmaf(p1.z, v2, fmaf(p1.w, v3, o1))));
  }
  const int q0b = qt * 32 + w * 2;
  out_vec[(size_t)(b * Q_ + q0b) * D_ + col] = o0;
  out_vec[(size_t)(b * Q_ + q0b + 1) * D_ + col] = o1;
}

extern "C" void kernel_launch(void* const* d_in, const int* in_sizes, int n_in,
                              void* d_out, int out_size, void* d_ws, size_t ws_size,
                              hipStream_t stream) {
  const float* query = (const float*)d_in[0];
  const float* key   = (const float*)d_in[1];
  const float* value = (const float*)d_in[2];
  const int*   mask  = (const int*)d_in[3];
  const float* W1    = (const float*)d_in[4];
  const float* b1    = (const float*)d_in[5];
  const float* w2    = (const float*)d_in[6];

  float* out_vec = (float*)d_out;                   // (8,128,512)
  float* out_w   = out_vec + (size_t)B_ * Q_ * D_;  // (8,128,256)

  float* qp   = (float*)d_ws;                           // 2 MB fp32 Eq [b][q][h]
  float* kpbT = qp + (size_t)B_ * Q_ * D_;              // 4 MB fp32 Ek [b][h][k]
  float* sc   = kpbT + (size_t)B_ * D_ * K_;            // 1 MB raw scores [b][q][k]

  gemm_kernel<<<dim3(8, 96), 256, 0, stream>>>(query, key, W1, b1, qp, kpbT);
  score_kernel<<<dim3(64, B_), 1024, 0, stream>>>(qp, kpbT, mask, w2, sc);
  pv_kernel<<<dim3(32, B_), 1024, 0, stream>>>(sc, value, out_w, out_vec);
}

// Round 11
// 113.062 us; speedup vs baseline: 1.0335x; 1.0335x over previous
//
#include <hip/hip_runtime.h>
#include <hip/hip_bf16.h>

#define B_ 8
#define Q_ 128
#define K_ 256
#define D_ 512
#define TWOLOG2E 2.8853900817779268f
#define SCALE 0.044194173824159216f   // 1/sqrt(512)
#define L2E 1.4426950408889634f
#define MASKVAL (-44194173.824159216f) // -1e9 * SCALE

typedef __attribute__((ext_vector_type(8))) short frag8;   // 8 bf16
typedef __attribute__((ext_vector_type(4))) float f32x4;

__device__ __forceinline__ float fexp2(float x) {
  float r;
  asm("v_exp_f32 %0, %1" : "=v"(r) : "v"(x));
  return r;
}
__device__ __forceinline__ float frcp(float x) {
  float r;
  asm("v_rcp_f32 %0, %1" : "=v"(r) : "v"(x));
  return r;
}
__device__ __forceinline__ unsigned f2bf_u(float x) {
  unsigned u = __float_as_uint(x);
  return (u + 0x7FFFu + ((u >> 16) & 1u)) >> 16;
}
__device__ __forceinline__ unsigned short f2bf(float x) {
  return (unsigned short)f2bf_u(x);
}
__device__ __forceinline__ unsigned packbf(float lo, float hi) {
  return f2bf_u(lo) | (f2bf_u(hi) << 16);
}

// ---------------- Kernel 1: fused convert + MFMA projection GEMM ----------------
// q-rows: qp[m][n] = exp(2*C)  (row-major [b][q][h])
// k-rows: kpbT[b][n][pos(k)] = exp(2*(C+b1[n])), MASK-COMPACTED along k:
//         pos(k) = #unmasked j<k; masked k not written.
__global__ __launch_bounds__(256) void gemm_kernel(
    const float* __restrict__ query, const float* __restrict__ key,
    const float* __restrict__ W1, const float* __restrict__ b1,
    const int* __restrict__ mask,
    float* __restrict__ qp, float* __restrict__ kpbT) {
  __shared__ short As[32 * 64];
  __shared__ short Bs[64 * 72];
  __shared__ int posm[K_];
  __shared__ int cnt4[4];
  const int t = threadIdx.x;
  const int m0 = blockIdx.y * 32;
  const int n0 = blockIdx.x * 64;
  const bool is_k = (m0 >= B_ * Q_);
  const float* X = is_k ? key : query;
  const int xrow0 = is_k ? (m0 - B_ * Q_) : m0;
  const float* Wb = W1 + (is_k ? (size_t)D_ * D_ : 0);

  const int am = t >> 3;
  const int ac = t & 7;
  const float* gA = X + (size_t)(xrow0 + am) * D_ + ac * 8;
  short* aw = As + am * 64 + ((ac ^ (am & 7)) * 8);

  const int prow = t >> 4;
  const int n4 = (t & 15) * 4;
  const float* gB = Wb + n0 + n4;

  const int l = t & 63;
  const int w = t >> 6;
  const int lr = l & 15;
  const int kg = l >> 4;
  const int key8 = lr & 7;
  int aoff[2][2], boff[2];
#pragma unroll
  for (int kk = 0; kk < 2; ++kk) {
    const int cposA = ((kg + kk * 4) ^ key8) * 8;
#pragma unroll
    for (int mt = 0; mt < 2; ++mt) aoff[mt][kk] = (mt * 16 + lr) * 64 + cposA;
    boff[kk] = (w * 16 + lr) * 72 + (kg + kk * 4) * 8;
  }

  f32x4 acc[2];
  acc[0] = (f32x4){0.f, 0.f, 0.f, 0.f};
  acc[1] = (f32x4){0.f, 0.f, 0.f, 0.f};

  for (int k0 = 0; k0 < D_; k0 += 64) {
    float4 a0 = *(const float4*)(gA + k0);
    float4 a1 = *(const float4*)(gA + k0 + 4);
    float4 w00 = *(const float4*)(gB + (size_t)(k0 + 2 * prow) * D_);
    float4 w01 = *(const float4*)(gB + (size_t)(k0 + 2 * prow + 1) * D_);
    float4 w10 = *(const float4*)(gB + (size_t)(k0 + 2 * prow + 32) * D_);
    float4 w11 = *(const float4*)(gB + (size_t)(k0 + 2 * prow + 33) * D_);
    __syncthreads();
    {
      union { frag8 f; unsigned short u[8]; } av;
      av.u[0] = f2bf(a0.x); av.u[1] = f2bf(a0.y); av.u[2] = f2bf(a0.z); av.u[3] = f2bf(a0.w);
      av.u[4] = f2bf(a1.x); av.u[5] = f2bf(a1.y); av.u[6] = f2bf(a1.z); av.u[7] = f2bf(a1.w);
      *(frag8*)aw = av.f;
    }
    {
      float lo0[4] = {w00.x, w00.y, w00.z, w00.w};
      float hi0[4] = {w01.x, w01.y, w01.z, w01.w};
      float lo1[4] = {w10.x, w10.y, w10.z, w10.w};
      float hi1[4] = {w11.x, w11.y, w11.z, w11.w};
#pragma unroll
      for (int j = 0; j < 4; ++j) {
        *(unsigned*)(Bs + (n4 + j) * 72 + 2 * prow) = packbf(lo0[j], hi0[j]);
        *(unsigned*)(Bs + (n4 + j) * 72 + 2 * (prow + 16)) = packbf(lo1[j], hi1[j]);
      }
    }
    __syncthreads();
#pragma unroll
    for (int kk = 0; kk < 2; ++kk) {
      frag8 bf = *(const frag8*)(Bs + boff[kk]);
#pragma unroll
      for (int mt = 0; mt < 2; ++mt) {
        frag8 af = *(const frag8*)(As + aoff[mt][kk]);
        acc[mt] = __builtin_amdgcn_mfma_f32_16x16x32_bf16(af, bf, acc[mt], 0, 0, 0);
      }
    }
  }

  const int col = n0 + w * 16 + lr;
  if (is_k) {
    const int bb = (m0 - B_ * Q_) >> 8;   // all 32 k-rows in same batch
    // build compacted positions for this batch's 256 k
    {
      // t in [0,256): wave w == chunk (t>>6), lane == k within chunk
      const bool um = (mask[bb * K_ + t] == 0);
      const unsigned long long bal = __ballot(um);
      const int pic = (int)__popcll(bal & ((1ull << l) - 1ull));
      posm[t] = um ? pic : -1;
      if (l == 0) cnt4[w] = (int)__popcll(bal);
    }
    __syncthreads();
    if (posm[t] >= 0) {
      int base = 0;
#pragma unroll
      for (int j = 0; j < 3; ++j)
        if (j < w) base += cnt4[j];
      posm[t] += base;
    }
    __syncthreads();

    const float bc = b1[col];
#pragma unroll
    for (int mt = 0; mt < 2; ++mt) {
      const int kk0 = (m0 - B_ * Q_ + mt * 16 + kg * 4) & 255;
      float vv[4];
      vv[0] = fexp2((acc[mt][0] + bc) * TWOLOG2E);
      vv[1] = fexp2((acc[mt][1] + bc) * TWOLOG2E);
      vv[2] = fexp2((acc[mt][2] + bc) * TWOLOG2E);
      vv[3] = fexp2((acc[mt][3] + bc) * TWOLOG2E);
#pragma unroll
      for (int i = 0; i < 4; ++i) {
        const int p = posm[kk0 + i];
        if (p >= 0) kpbT[((size_t)bb * D_ + col) * K_ + p] = vv[i];
      }
    }
  } else {
#pragma unroll
    for (int mt = 0; mt < 2; ++mt) {
#pragma unroll
      for (int i = 0; i < 4; ++i) {
        const int row = m0 + mt * 16 + kg * 4 + i;
        qp[(size_t)row * D_ + col] = fexp2(acc[mt][i] * TWOLOG2E);
      }
    }
  }
}

// ---------------- Kernel 2: fused tanh-score + softmax + PV (mask-compacted) ----
// qp holds Eq; kpbT holds compacted Ek (slots [0,M) = unmasked k in order).
// 1024 thr = 16 waves, 4 q-rows/block, grid (32, 8).
// M<=128: wave w -> h-chunk w*32, slots 2*lane (half the phase-1 work).
// M>128 : R8 mapping: kc=w&1 slot-half, h-chunk (w>>1)*64.
__global__ __launch_bounds__(1024) void attn_kernel(
    const float* __restrict__ qp, const float* __restrict__ kpbT,
    const float* __restrict__ value, const int* __restrict__ mask,
    const float* __restrict__ w2,
    float* __restrict__ out_vec, float* __restrict__ out_w) {
  __shared__ float smem_p[16 * 512];  // [w][q(4)][128 local slots]  32 KB
  __shared__ float pw[4 * 256];       // scores -> weights [q][k]
  __shared__ int idxl[K_];
  __shared__ int sM;
  const int b = blockIdx.y;
  const int q0 = blockIdx.x * 4;
  const int t = threadIdx.x;
  const int lane = t & 63;
  const int w = __builtin_amdgcn_readfirstlane(t >> 6);  // 0..15

  // ---- phase 0: compaction index list (wave 0)
  if (w == 0) {
    int base = 0;
#pragma unroll
    for (int c = 0; c < 4; ++c) {
      const int k = c * 64 + lane;
      const int mk = mask[b * K_ + k];
      const unsigned long long bal = __ballot(mk == 0);
      const int pos = (int)__popcll(bal & ((1ull << lane) - 1ull));
      if (mk == 0) idxl[base + pos] = k;
      base += (int)__popcll(bal);
    }
    if (lane == 0) sM = base;
  }
  __syncthreads();
  const int M = sM;
  const bool big = (M > 128);
  const int kc = big ? (w & 1) : 0;
  const int h0 = big ? (w >> 1) * 64 : w * 32;
  const int hlen = big ? 64 : 32;

  // ---- phase 1: partials over (compacted slots, h-range)
  {
    const float* pk = kpbT + ((size_t)b * D_ + h0) * K_ + kc * 128 + 2 * lane;
    const float* q_0 = qp + (size_t)(b * Q_ + q0 + 0) * D_ + h0;
    const float* q_1 = qp + (size_t)(b * Q_ + q0 + 1) * D_ + h0;
    const float* q_2 = qp + (size_t)(b * Q_ + q0 + 2) * D_ + h0;
    const float* q_3 = qp + (size_t)(b * Q_ + q0 + 3) * D_ + h0;
    const float* w2h = w2 + h0;

    float2 a0 = {0.f, 0.f}, a1 = {0.f, 0.f}, a2 = {0.f, 0.f}, a3 = {0.f, 0.f};
    for (int h = 0; h < hlen; h += 8) {
      float2 kv[8];
#pragma unroll
      for (int j = 0; j < 8; ++j) kv[j] = *(const float2*)&pk[(size_t)(h + j) * K_];
      float4 e0a = *(const float4*)(q_0 + h), e0b = *(const float4*)(q_0 + h + 4);
      float4 e1a = *(const float4*)(q_1 + h), e1b = *(const float4*)(q_1 + h + 4);
      float4 e2a = *(const float4*)(q_2 + h), e2b = *(const float4*)(q_2 + h + 4);
      float4 e3a = *(const float4*)(q_3 + h), e3b = *(const float4*)(q_3 + h + 4);
      float4 wa = *(const float4*)(w2h + h), wb = *(const float4*)(w2h + h + 4);
      float E0[8] = {e0a.x, e0a.y, e0a.z, e0a.w, e0b.x, e0b.y, e0b.z, e0b.w};
      float E1[8] = {e1a.x, e1a.y, e1a.z, e1a.w, e1b.x, e1b.y, e1b.z, e1b.w};
      float E2[8] = {e2a.x, e2a.y, e2a.z, e2a.w, e2b.x, e2b.y, e2b.z, e2b.w};
      float E3[8] = {e3a.x, e3a.y, e3a.z, e3a.w, e3b.x, e3b.y, e3b.z, e3b.w};
      float WV[8] = {wa.x, wa.y, wa.z, wa.w, wb.x, wb.y, wb.z, wb.w};
#pragma unroll
      for (int j = 0; j < 8; ++j) {
        a0.x = fmaf(WV[j], frcp(fmaf(E0[j], kv[j].x, 1.f)), a0.x);
        a0.y = fmaf(WV[j], frcp(fmaf(E0[j], kv[j].y, 1.f)), a0.y);
        a1.x = fmaf(WV[j], frcp(fmaf(E1[j], kv[j].x, 1.f)), a1.x);
        a1.y = fmaf(WV[j], frcp(fmaf(E1[j], kv[j].y, 1.f)), a1.y);
        a2.x = fmaf(WV[j], frcp(fmaf(E2[j], kv[j].x, 1.f)), a2.x);
        a2.y = fmaf(WV[j], frcp(fmaf(E2[j], kv[j].y, 1.f)), a2.y);
        a3.x = fmaf(WV[j], frcp(fmaf(E3[j], kv[j].x, 1.f)), a3.x);
        a3.y = fmaf(WV[j], frcp(fmaf(E3[j], kv[j].y, 1.f)), a3.y);
      }
    }
    *(float2*)&smem_p[w * 512 + 0 * 128 + 2 * lane] = a0;
    *(float2*)&smem_p[w * 512 + 1 * 128 + 2 * lane] = a1;
    *(float2*)&smem_p[w * 512 + 2 * 128 + 2 * lane] = a2;
    *(float2*)&smem_p[w * 512 + 3 * 128 + 2 * lane] = a3;
  }
  __syncthreads();

  // ---- phase 2: combine + scatter + softmax; wave q (0..3)
  if (w < 4) {
    const int q = w;
    float sw = 0.f;
#pragma unroll
    for (int m = 0; m < 8; ++m) sw += w2[lane + 64 * m];
#pragma unroll
    for (int off = 32; off; off >>= 1) sw += __shfl_xor(sw, off);

    // init scores to MASKVAL
#pragma unroll
    for (int r = 0; r < 4; ++r) pw[q * 256 + r * 64 + lane] = MASKVAL;
    // combine partials for valid slots, scatter to original k
#pragma unroll
    for (int r = 0; r < 4; ++r) {
      const int slot = r * 64 + lane;
      float p = 0.f;
      if (big) {
        const int kcc = r >> 1;
        const int off = (r & 1) * 64 + lane;
#pragma unroll
        for (int i = 0; i < 8; ++i)
          p += smem_p[(2 * i + kcc) * 512 + q * 128 + off];
      } else {
        if (r < 2) {
#pragma unroll
          for (int ww = 0; ww < 16; ++ww)
            p += smem_p[ww * 512 + q * 128 + slot];
        }
      }
      const bool valid = (slot < M) && (big || r < 2);
      if (valid) pw[q * 256 + idxl[slot]] = fmaf(-2.f, p, sw) * SCALE;
    }

    float sv[4];
#pragma unroll
    for (int r = 0; r < 4; ++r) sv[r] = pw[q * 256 + r * 64 + lane];
    float mx = fmaxf(fmaxf(sv[0], sv[1]), fmaxf(sv[2], sv[3]));
#pragma unroll
    for (int off = 32; off; off >>= 1) mx = fmaxf(mx, __shfl_xor(mx, off));
    float e[4], sum = 0.f;
#pragma unroll
    for (int r = 0; r < 4; ++r) {
      e[r] = fexp2((sv[r] - mx) * L2E);
      sum += e[r];
    }
#pragma unroll
    for (int off = 32; off; off >>= 1) sum += __shfl_xor(sum, off);
    const float inv = frcp(sum);
    float* ow = out_w + (size_t)(b * Q_ + q0 + q) * K_;
#pragma unroll
    for (int r = 0; r < 4; ++r) {
      const float p = e[r] * inv;
      pw[q * 256 + r * 64 + lane] = p;
      ow[r * 64 + lane] = p;
    }
  }
  __syncthreads();

  // ---- phase 3: PV. thread t -> col = t&511, q-pair qq = t>>9
  const int col = t & 511;
  const int qq = t >> 9;
  float o0 = 0.f, o1 = 0.f;
  const float* vb = value + (size_t)b * K_ * D_;
  for (int k = 0; k < K_; k += 4) {
    const float4 p0 = *(const float4*)&pw[(qq * 2 + 0) * 256 + k];
    const float4 p1 = *(const float4*)&pw[(qq * 2 + 1) * 256 + k];
    const float v0 = vb[(size_t)(k + 0) * D_ + col];
    const float v1 = vb[(size_t)(k + 1) * D_ + col];
    const float v2 = vb[(size_t)(k + 2) * D_ + col];
    const float v3 = vb[(size_t)(k + 3) * D_ + col];
    o0 = fmaf(p0.x, v0, fmaf(p0.y, v1, fmaf(p0.z, v2, fmaf(p0.w, v3, o0))));
    o1 = fmaf(p1.x, v0, fmaf(p1.y, v1, fmaf(p1.z, v2, fmaf(p1.w, v3, o1))));
  }
  out_vec[(size_t)(b * Q_ + q0 + qq * 2 + 0) * D_ + col] = o0;
  out_vec[(size_t)(b * Q_ + q0 + qq * 2 + 1) * D_ + col] = o1;
}

extern "C" void kernel_launch(void* const* d_in, const int* in_sizes, int n_in,
                              void* d_out, int out_size, void* d_ws, size_t ws_size,
                              hipStream_t stream) {
  const float* query = (const float*)d_in[0];
  const float* key   = (const float*)d_in[1];
  const float* value = (const float*)d_in[2];
  const int*   mask  = (const int*)d_in[3];
  const float* W1    = (const float*)d_in[4];
  const float* b1    = (const float*)d_in[5];
  const float* w2    = (const float*)d_in[6];

  float* out_vec = (float*)d_out;                   // (8,128,512)
  float* out_w   = out_vec + (size_t)B_ * Q_ * D_;  // (8,128,256)

  float* qp   = (float*)d_ws;                       // 2 MB fp32 Eq [b][q][h]
  float* kpbT = qp + (size_t)B_ * Q_ * D_;          // 4 MB fp32 Ek compacted [b][h][slot]

  gemm_kernel<<<dim3(8, 96), 256, 0, stream>>>(query, key, W1, b1, mask, qp, kpbT);
  attn_kernel<<<dim3(Q_ / 4, B_), 1024, 0, stream>>>(qp, kpbT, value, mask, w2,
                                                     out_vec, out_w);
}